// Round 3
// baseline (584.141 us; speedup 1.0000x reference)
//
#include <hip/hip_runtime.h>

#define LSEQ 8192
#define MFFT 16384      // 2*L = 16*16*16*4
#define NT 1024
#define CCH 2048
#define TWO_PI 6.283185307179586f

// XOR bank swizzle: conflict-free for all pass access patterns.
__device__ __forceinline__ int SL(int i) { return i ^ ((i >> 4) & 15); }

__device__ __forceinline__ float2 cmul(float2 a, float2 b) {
    return make_float2(fmaf(a.x, b.x, -a.y * b.y), fmaf(a.x, b.y, a.y * b.x));
}

template<int SGN>
__device__ __forceinline__ void dft4(float2& a0, float2& a1, float2& a2, float2& a3) {
    float t0x = a0.x + a2.x, t0y = a0.y + a2.y;
    float t1x = a0.x - a2.x, t1y = a0.y - a2.y;
    float t2x = a1.x + a3.x, t2y = a1.y + a3.y;
    float t3x = a1.x - a3.x, t3y = a1.y - a3.y;
    float ux = (SGN < 0) ? t3y : -t3y;   // u = SGN*i*t3
    float uy = (SGN < 0) ? -t3x : t3x;
    a0 = make_float2(t0x + t2x, t0y + t2y);
    a1 = make_float2(t1x + ux, t1y + uy);
    a2 = make_float2(t0x - t2x, t0y - t2y);
    a3 = make_float2(t1x - ux, t1y - uy);
}

// Radix-16 DFT on registers: X[k] ends at v[4*(k&3)+(k>>2)].
template<int SGN>
__device__ __forceinline__ void dft16(float2 v[16]) {
    dft4<SGN>(v[0], v[4], v[8],  v[12]);
    dft4<SGN>(v[1], v[5], v[9],  v[13]);
    dft4<SGN>(v[2], v[6], v[10], v[14]);
    dft4<SGN>(v[3], v[7], v[11], v[15]);
    const float sg = (float)SGN;
    const float C1 = 0.92387953251f, S1 = 0.38268343236f, C2 = 0.70710678119f;
    const float2 w1 = make_float2( C1,  sg * S1);
    const float2 w2 = make_float2( C2,  sg * C2);
    const float2 w3 = make_float2( S1,  sg * C1);
    const float2 w6 = make_float2(-C2,  sg * C2);
    const float2 w9 = make_float2(-C1, -sg * S1);
    v[5]  = cmul(v[5],  w1);
    v[6]  = cmul(v[6],  w2);
    v[7]  = cmul(v[7],  w3);
    v[9]  = cmul(v[9],  w2);
    v[10] = make_float2(-sg * v[10].y, sg * v[10].x);   // *W16^4
    v[11] = cmul(v[11], w6);
    v[13] = cmul(v[13], w3);
    v[14] = cmul(v[14], w6);
    v[15] = cmul(v[15], w9);
    dft4<SGN>(v[0],  v[1],  v[2],  v[3]);
    dft4<SGN>(v[4],  v[5],  v[6],  v[7]);
    dft4<SGN>(v[8],  v[9],  v[10], v[11]);
    dft4<SGN>(v[12], v[13], v[14], v[15]);
}

// One Stockham radix-16 pass. ZTOP: input elements >= MFFT/2 are known zero
// (zero-padded input) -> skip those reads, and loaders need not zero-fill.
template<int SGN, int NS, bool ZTOP>
__device__ __forceinline__ void pass16(float2* ds, int tid) {
    const int j = tid;
    float2 v[16];
    if constexpr (ZTOP) {
#pragma unroll
        for (int r = 0; r < 8; r++) v[r] = ds[SL(j + (r << 10))];
#pragma unroll
        for (int r = 8; r < 16; r++) v[r] = make_float2(0.f, 0.f);
    } else {
#pragma unroll
        for (int r = 0; r < 16; r++) v[r] = ds[SL(j + (r << 10))];
    }

    if constexpr (NS > 1) {
        const float kang = (float)SGN * TWO_PI / (float)(NS * 16);
        float ang = kang * (float)(j & (NS - 1));
        float s1, c1;
        __sincosf(ang, &s1, &c1);
        float2 wstep = make_float2(c1, s1);
        float2 w = wstep;
        v[1] = cmul(v[1], w);
#pragma unroll
        for (int r = 2; r < 16; r++) { w = cmul(w, wstep); v[r] = cmul(v[r], w); }
    }

    dft16<SGN>(v);
    __syncthreads();                       // all reads done before scatter
    const int idxD = ((j & ~(NS - 1)) << 4) | (j & (NS - 1));
#pragma unroll
    for (int kk = 0; kk < 16; kk++)
        ds[SL(idxD + kk * NS)] = v[4 * (kk & 3) + (kk >> 2)];
    __syncthreads();
}

// First inverse pass: identical to pass16<SGN,1,false> but input comes from
// registers (thread t holds natural elements {t + s*1024}) -> no LDS read.
template<int SGN>
__device__ __forceinline__ void pass16_reg(float2* ds, int tid, float2 v[16]) {
    dft16<SGN>(v);
    __syncthreads();                       // all pass4_keep reads done
    const int idxD = tid << 4;
#pragma unroll
    for (int kk = 0; kk < 16; kk++)
        ds[SL(idxD + kk)] = v[4 * (kk & 3) + (kk >> 2)];
    __syncthreads();
}

// Final forward pass (radix-4, NS=4096), outputs kept in registers:
// out[s] = scale * X[tid + s*1024]. Reads are residue-class-local (no barrier).
template<int SGN>
__device__ __forceinline__ void pass4_keep(const float2* ds, int tid,
                                           float2 out[16], float scale) {
    const float kang = (float)SGN * TWO_PI / (float)MFFT;
#pragma unroll
    for (int b = 0; b < 4; b++) {
        int j = tid + (b << 10);
        float2 a0 = ds[SL(j)];
        float2 a1 = ds[SL(j + 4096)];
        float2 a2 = ds[SL(j + 8192)];
        float2 a3 = ds[SL(j + 12288)];
        float s1, c1;
        __sincosf(kang * (float)j, &s1, &c1);
        float2 w1 = make_float2(c1, s1);
        float2 w2 = cmul(w1, w1);
        float2 w3 = cmul(w2, w1);
        a1 = cmul(a1, w1); a2 = cmul(a2, w2); a3 = cmul(a3, w3);
        dft4<SGN>(a0, a1, a2, a3);
        out[b]      = make_float2(a0.x * scale, a0.y * scale);
        out[b + 4]  = make_float2(a1.x * scale, a1.y * scale);
        out[b + 8]  = make_float2(a2.x * scale, a2.y * scale);
        out[b + 12] = make_float2(a3.x * scale, a3.y * scale);
    }
}

// Final inverse pass (radix-4): compute only elements < LSEQ and store straight
// to global: y0 = Re(z), y1 = Im(z). Reads class-local, no barrier needed.
__device__ __forceinline__ void pass4_store(const float2* ds, int tid,
                                            float* __restrict__ y0p,
                                            float* __restrict__ y1p) {
    const float kang = TWO_PI / (float)MFFT;          // SGN = +1
#pragma unroll
    for (int b = 0; b < 4; b++) {
        int j = tid + (b << 10);
        float2 a0 = ds[SL(j)];
        float2 a1 = ds[SL(j + 4096)];
        float2 a2 = ds[SL(j + 8192)];
        float2 a3 = ds[SL(j + 12288)];
        float s1, c1;
        __sincosf(kang * (float)j, &s1, &c1);
        float2 w1 = make_float2(c1, s1);
        float2 w2 = cmul(w1, w1);
        float2 w3 = cmul(w2, w1);
        a1 = cmul(a1, w1); a2 = cmul(a2, w2); a3 = cmul(a3, w3);
        float t0x = a0.x + a2.x, t0y = a0.y + a2.y;
        float t1x = a0.x - a2.x, t1y = a0.y - a2.y;
        float t2x = a1.x + a3.x, t2y = a1.y + a3.y;
        float t3x = a1.x - a3.x, t3y = a1.y - a3.y;
        // outputs j (o0 = t0+t2) and j+4096 (o1 = t1 + i*t3); j+8192.. discarded
        y0p[j]        = t0x + t2x;
        y1p[j]        = t0y + t2y;
        y0p[j + 4096] = t1x - t3y;
        y1p[j + 4096] = t1y + t3x;
    }
}

__global__ __launch_bounds__(NT, 4)
void hyena_fftconv(const float* __restrict__ x,
                   const float* __restrict__ k,
                   const float* __restrict__ bias,
                   float* __restrict__ y)
{
    __shared__ float2 ds[MFFT];              // 128 KiB

    const int c   = blockIdx.x;              // one block per channel
    const int tid = threadIdx.x;

    const float* kp  = k + (size_t)c * LSEQ;
    const float* x0p = x + (size_t)c * LSEQ;                 // batch 0
    const float* x1p = x + ((size_t)(CCH + c)) * LSEQ;       // batch 1
    float*       y0p = y + (size_t)c * LSEQ;
    float*       y1p = y + ((size_t)(CCH + c)) * LSEQ;
    const float  b0  = bias[c];

    // ---- K = FFT(k + i*0)/M, bias folded into k[0] (s=0 conv tap) ----
#pragma unroll
    for (int s = 0; s < 8; s++) {
        int m = tid + (s << 10);
        float kv = kp[m];
        if (m == 0) kv += b0;
        ds[SL(m)] = make_float2(kv, 0.f);    // class-local; top half never read
    }
    pass16<-1, 1,   true >(ds, tid);
    pass16<-1, 16,  false>(ds, tid);
    pass16<-1, 256, false>(ds, tid);
    float2 kreg[16];
    pass4_keep<-1>(ds, tid, kreg, 1.0f / (float)MFFT);   // K in registers

    // ---- A = FFT(x0 + i*x1)  (linear: A = X0 + i*X1) ----
#pragma unroll
    for (int s = 0; s < 8; s++) {
        int m = tid + (s << 10);
        ds[SL(m)] = make_float2(x0p[m], x1p[m]);         // class-local
    }
    pass16<-1, 1,   true >(ds, tid);
    pass16<-1, 16,  false>(ds, tid);
    pass16<-1, 256, false>(ds, tid);
    float2 z[16];
    pass4_keep<-1>(ds, tid, z, 1.0f);                    // A in registers

    // ---- Z = A*K = Y0 + i*Y1  (K Hermitian; pure register cmuls) ----
#pragma unroll
    for (int s = 0; s < 16; s++) z[s] = cmul(z[s], kreg[s]);

    // ---- z = IFFT(Z): y0 = Re, y1 = Im; last pass writes straight to HBM ----
    pass16_reg<1>(ds, tid, z);
    pass16<1, 16,  false>(ds, tid);
    pass16<1, 256, false>(ds, tid);
    pass4_store(ds, tid, y0p, y1p);
}

extern "C" void kernel_launch(void* const* d_in, const int* in_sizes, int n_in,
                              void* d_out, int out_size, void* d_ws, size_t ws_size,
                              hipStream_t stream) {
    const float* x    = (const float*)d_in[0];
    const float* k    = (const float*)d_in[1];
    const float* bias = (const float*)d_in[2];
    float* y          = (float*)d_out;

    hyena_fftconv<<<dim3(CCH), dim3(NT), 0, stream>>>(x, k, bias, y);
}

// Round 4
// 408.690 us; speedup vs baseline: 1.4293x; 1.4293x over previous
//
#include <hip/hip_runtime.h>

#define LSEQ 8192
#define MFFT 16384      // 2*L = 16*16*16*4
#define NT 1024
#define CCH 2048
#define TWO_PI 6.283185307179586f

// XOR bank swizzle: conflict-free for all pass access patterns.
__device__ __forceinline__ int SL(int i) { return i ^ ((i >> 4) & 15); }

__device__ __forceinline__ float2 cmul(float2 a, float2 b) {
    return make_float2(fmaf(a.x, b.x, -a.y * b.y), fmaf(a.x, b.y, a.y * b.x));
}
__device__ __forceinline__ float2 conjf2(float2 a) { return make_float2(a.x, -a.y); }

template<int SGN>
__device__ __forceinline__ void dft4(float2& a0, float2& a1, float2& a2, float2& a3) {
    float t0x = a0.x + a2.x, t0y = a0.y + a2.y;
    float t1x = a0.x - a2.x, t1y = a0.y - a2.y;
    float t2x = a1.x + a3.x, t2y = a1.y + a3.y;
    float t3x = a1.x - a3.x, t3y = a1.y - a3.y;
    float ux = (SGN < 0) ? t3y : -t3y;   // u = SGN*i*t3
    float uy = (SGN < 0) ? -t3x : t3x;
    a0 = make_float2(t0x + t2x, t0y + t2y);
    a1 = make_float2(t1x + ux, t1y + uy);
    a2 = make_float2(t0x - t2x, t0y - t2y);
    a3 = make_float2(t1x - ux, t1y - uy);
}

// Radix-16 DFT on registers: X[k] ends at v[4*(k&3)+(k>>2)].
template<int SGN>
__device__ __forceinline__ void dft16(float2 v[16]) {
    dft4<SGN>(v[0], v[4], v[8],  v[12]);
    dft4<SGN>(v[1], v[5], v[9],  v[13]);
    dft4<SGN>(v[2], v[6], v[10], v[14]);
    dft4<SGN>(v[3], v[7], v[11], v[15]);
    const float sg = (float)SGN;
    const float C1 = 0.92387953251f, S1 = 0.38268343236f, C2 = 0.70710678119f;
    const float2 w1 = make_float2( C1,  sg * S1);
    const float2 w2 = make_float2( C2,  sg * C2);
    const float2 w3 = make_float2( S1,  sg * C1);
    const float2 w6 = make_float2(-C2,  sg * C2);
    const float2 w9 = make_float2(-C1, -sg * S1);
    v[5]  = cmul(v[5],  w1);
    v[6]  = cmul(v[6],  w2);
    v[7]  = cmul(v[7],  w3);
    v[9]  = cmul(v[9],  w2);
    v[10] = make_float2(-sg * v[10].y, sg * v[10].x);   // *W16^4
    v[11] = cmul(v[11], w6);
    v[13] = cmul(v[13], w3);
    v[14] = cmul(v[14], w6);
    v[15] = cmul(v[15], w9);
    dft4<SGN>(v[0],  v[1],  v[2],  v[3]);
    dft4<SGN>(v[4],  v[5],  v[6],  v[7]);
    dft4<SGN>(v[8],  v[9],  v[10], v[11]);
    dft4<SGN>(v[12], v[13], v[14], v[15]);
}

// First pass (NS=1), input already in registers (natural elems {tid + r*1024}).
// Barrier before scatter protects any preceding LDS reads.
template<int SGN>
__device__ __forceinline__ void pass16_core(float2* ds, int tid, float2 v[16]) {
    dft16<SGN>(v);
    __syncthreads();
    const int idxD = tid << 4;
#pragma unroll
    for (int kk = 0; kk < 16; kk++)
        ds[SL(idxD + kk)] = v[4 * (kk & 3) + (kk >> 2)];
    __syncthreads();
}

// Mid pass, LDS -> LDS (NS = 16 or 256).
template<int SGN, int NS>
__device__ __forceinline__ void pass16(float2* ds, int tid) {
    const int j = tid;
    float2 v[16];
#pragma unroll
    for (int r = 0; r < 16; r++) v[r] = ds[SL(j + (r << 10))];

    const float kang = (float)SGN * TWO_PI / (float)(NS * 16);
    float ang = kang * (float)(j & (NS - 1));
    float s1, c1;
    __sincosf(ang, &s1, &c1);
    float2 wstep = make_float2(c1, s1);
    float2 w = wstep;
    v[1] = cmul(v[1], w);
#pragma unroll
    for (int r = 2; r < 16; r++) { w = cmul(w, wstep); v[r] = cmul(v[r], w); }

    dft16<SGN>(v);
    __syncthreads();
    const int idxD = ((j & ~(NS - 1)) << 4) | (j & (NS - 1));
#pragma unroll
    for (int kk = 0; kk < 16; kk++)
        ds[SL(idxD + kk * NS)] = v[4 * (kk & 3) + (kk >> 2)];
    __syncthreads();
}

// Final forward radix-4 pass, in place. Class-local (thread t touches only
// slots {t + s*1024}); caller adds the barrier after.
template<int SGN>
__device__ __forceinline__ void pass4_lds(float2* ds, int tid) {
    const float kang = (float)SGN * TWO_PI / (float)MFFT;
#pragma unroll
    for (int b = 0; b < 4; b++) {
        int j = tid + (b << 10);
        float2 a0 = ds[SL(j)];
        float2 a1 = ds[SL(j + 4096)];
        float2 a2 = ds[SL(j + 8192)];
        float2 a3 = ds[SL(j + 12288)];
        float s1, c1;
        __sincosf(kang * (float)j, &s1, &c1);
        float2 w1 = make_float2(c1, s1);
        float2 w2 = cmul(w1, w1), w3 = cmul(w2, w1);
        a1 = cmul(a1, w1); a2 = cmul(a2, w2); a3 = cmul(a3, w3);
        dft4<SGN>(a0, a1, a2, a3);
        ds[SL(j)]         = a0;
        ds[SL(j + 4096)]  = a1;
        ds[SL(j + 8192)]  = a2;
        ds[SL(j + 12288)] = a3;
    }
}

// Final forward radix-4 pass for K: keep only bins {tid + r*1024, r=0..8}
// (Hermitian half) scaled by sc. Pure class-local reads, nothing written.
template<int SGN>
__device__ __forceinline__ void pass4_keepK(const float2* ds, int tid,
                                            float2 kreg[9], float sc) {
    const float kang = (float)SGN * TWO_PI / (float)MFFT;
#pragma unroll
    for (int b = 0; b < 4; b++) {
        int j = tid + (b << 10);
        float2 a0 = ds[SL(j)];
        float2 a1 = ds[SL(j + 4096)];
        float2 a2 = ds[SL(j + 8192)];
        float2 a3 = ds[SL(j + 12288)];
        float s1, c1;
        __sincosf(kang * (float)j, &s1, &c1);
        float2 w1 = make_float2(c1, s1);
        float2 w2 = cmul(w1, w1), w3 = cmul(w2, w1);
        a1 = cmul(a1, w1); a2 = cmul(a2, w2); a3 = cmul(a3, w3);
        dft4<SGN>(a0, a1, a2, a3);
        kreg[b]     = make_float2(a0.x * sc, a0.y * sc);
        kreg[b + 4] = make_float2(a1.x * sc, a1.y * sc);
        if (b == 0) kreg[8] = make_float2(a2.x * sc, a2.y * sc);
    }
}

// Final inverse radix-4: compute only elements < LSEQ, store to global.
__device__ __forceinline__ void pass4_store(const float2* ds, int tid,
                                            float* __restrict__ y0p,
                                            float* __restrict__ y1p) {
    const float kang = TWO_PI / (float)MFFT;          // SGN = +1
#pragma unroll
    for (int b = 0; b < 4; b++) {
        int j = tid + (b << 10);
        float2 a0 = ds[SL(j)];
        float2 a1 = ds[SL(j + 4096)];
        float2 a2 = ds[SL(j + 8192)];
        float2 a3 = ds[SL(j + 12288)];
        float s1, c1;
        __sincosf(kang * (float)j, &s1, &c1);
        float2 w1 = make_float2(c1, s1);
        float2 w2 = cmul(w1, w1), w3 = cmul(w2, w1);
        a1 = cmul(a1, w1); a2 = cmul(a2, w2); a3 = cmul(a3, w3);
        float t0x = a0.x + a2.x, t0y = a0.y + a2.y;
        float t1x = a0.x - a2.x, t1y = a0.y - a2.y;
        float t2x = a1.x + a3.x, t2y = a1.y + a3.y;
        float t3x = a1.x - a3.x, t3y = a1.y - a3.y;
        y0p[j]        = t0x + t2x;          // bin j
        y1p[j]        = t0y + t2y;
        y0p[j + 4096] = t1x - t3y;          // bin j+4096 = t1 + i*t3
        y1p[j + 4096] = t1y + t3x;
    }
}

__global__ __launch_bounds__(NT)
void hyena_fftconv(const float* __restrict__ x,
                   const float* __restrict__ k,
                   const float* __restrict__ bias,
                   float* __restrict__ y)
{
    __shared__ float2 ds[MFFT];              // 128 KiB

    const int c   = blockIdx.x;              // one block per channel
    const int tid = threadIdx.x;

    const float* kp  = k + (size_t)c * LSEQ;
    const float* x0p = x + (size_t)c * LSEQ;                 // batch 0
    const float* x1p = x + ((size_t)(CCH + c)) * LSEQ;       // batch 1
    float*       y0p = y + (size_t)c * LSEQ;
    float*       y1p = y + ((size_t)(CCH + c)) * LSEQ;
    const float  b0  = bias[c];

    // ================= K = FFT(k)/M, bias folded into tap s=0 =================
    {
        float2 v[16];
#pragma unroll
        for (int s = 0; s < 8; s++) {
            int m = tid + (s << 10);
            float kv = kp[m];
            if (m == 0) kv += b0;
            v[s] = make_float2(kv, 0.f);
        }
#pragma unroll
        for (int s = 8; s < 16; s++) v[s] = make_float2(0.f, 0.f);
        pass16_core<-1>(ds, tid, v);         // pass 1 (global -> LDS)
    }
    pass16<-1, 16 >(ds, tid);
    pass16<-1, 256>(ds, tid);
    float2 kreg[9];
    pass4_keepK<-1>(ds, tid, kreg, 1.0f / (float)MFFT);   // Hermitian half in regs

    // ================= A = FFT(x0 + i*x1) =================
    {
        float2 v[16];
#pragma unroll
        for (int s = 0; s < 8; s++) {
            int m = tid + (s << 10);
            v[s] = make_float2(x0p[m], x1p[m]);
        }
#pragma unroll
        for (int s = 8; s < 16; s++) v[s] = make_float2(0.f, 0.f);
        pass16_core<-1>(ds, tid, v);         // its internal barrier protects keepK reads
    }
    pass16<-1, 16 >(ds, tid);
    pass16<-1, 256>(ds, tid);
    pass4_lds<-1>(ds, tid);                  // A natural-order in LDS
    __syncthreads();

    // ===== Z[j] = A[j]*K[j], Z[M-j] = A[M-j]*conj(K[j])  (K Hermitian) =====
    {
        // r = 0 (j = tid; tid==0 is the self-paired DC bin)
        float2 A = ds[SL(tid)];
        if (tid == 0) {
            ds[SL(0)] = cmul(A, kreg[0]);
        } else {
            int jm = MFFT - tid;
            float2 Am = ds[SL(jm)];
            ds[SL(tid)] = cmul(A,  kreg[0]);
            ds[SL(jm)]  = cmul(Am, conjf2(kreg[0]));
        }
#pragma unroll
        for (int r = 1; r < 8; r++) {
            int j  = tid + (r << 10);        // 1024..8191
            int jm = MFFT - j;               // 8193..15360
            float2 Aj = ds[SL(j)];
            float2 Am = ds[SL(jm)];
            ds[SL(j)]  = cmul(Aj, kreg[r]);
            ds[SL(jm)] = cmul(Am, conjf2(kreg[r]));
        }
        if (tid == 0) {                      // Nyquist bin j = 8192, self-paired
            float2 A8 = ds[SL(8192)];
            ds[SL(8192)] = cmul(A8, kreg[8]);
        }
    }
    __syncthreads();

    // ================= z = IFFT(Z): y0 = Re, y1 = Im =================
    {
        float2 v[16];
#pragma unroll
        for (int r = 0; r < 16; r++) v[r] = ds[SL(tid + (r << 10))];
        pass16_core<1>(ds, tid, v);          // NS=1, no twiddle
    }
    pass16<1, 16 >(ds, tid);
    pass16<1, 256>(ds, tid);
    pass4_store(ds, tid, y0p, y1p);
}

extern "C" void kernel_launch(void* const* d_in, const int* in_sizes, int n_in,
                              void* d_out, int out_size, void* d_ws, size_t ws_size,
                              hipStream_t stream) {
    const float* x    = (const float*)d_in[0];
    const float* k    = (const float*)d_in[1];
    const float* bias = (const float*)d_in[2];
    float* y          = (float*)d_out;

    hyena_fftconv<<<dim3(CCH), dim3(NT), 0, stream>>>(x, k, bias, y);
}